// Round 1
// baseline (478.702 us; speedup 1.0000x reference)
//
#include <hip/hip_runtime.h>
#include <hip/hip_bf16.h>

// EmbeddingToExpression: out[a,b] = sigmoid(E[a,b,:] @ W1[rix[b]] + b1[rix[b]]) @ W2[rix[b]] + b2[rix[b]]
// A = 4096 cells, B = 4096 regions_b, NE = 5, NI = 5.
// Memory-bound: 335 MB E read + 67 MB out write => ~64 us floor at 6.3 TB/s.

#define NA 4096
#define NB 4096
#define NE 5
#define NI 5
#define ROWS 32   // rows of 'a' handled per block

__global__ __launch_bounds__(256) void e2e_kernel(
    const float* __restrict__ E,     // [NA, NB, NE]
    const int*   __restrict__ rix,   // [NB]
    const float* __restrict__ w1,    // [R, NE, NI]
    const float* __restrict__ b1,    // [R, NI]
    const float* __restrict__ w2,    // [R, NI, 1]
    const float* __restrict__ b2,    // [R, 1]
    float*       __restrict__ out)   // [NA, NB]
{
    const int b  = blockIdx.x * 256 + threadIdx.x;   // region_b column
    const int a0 = blockIdx.y * ROWS;                // first row of 'a'

    const int r = rix[b];

    // Gather per-region params into registers (36 floats), amortized over ROWS rows.
    float W1[NE][NI];
    const float* w1p = w1 + (size_t)r * (NE * NI);
#pragma unroll
    for (int c = 0; c < NE; ++c)
#pragma unroll
        for (int d = 0; d < NI; ++d)
            W1[c][d] = w1p[c * NI + d];

    float B1[NI], W2[NI];
    const float* b1p = b1 + (size_t)r * NI;
    const float* w2p = w2 + (size_t)r * NI;
#pragma unroll
    for (int d = 0; d < NI; ++d) {
        B1[d] = b1p[d];
        W2[d] = w2p[d];
    }
    const float B2 = b2[r];

    const float* erow = E + ((size_t)a0 * NB + (size_t)b) * NE;
    float*       orow = out + (size_t)a0 * NB + b;

#pragma unroll 4
    for (int i = 0; i < ROWS; ++i) {
        // 5 consecutive floats; lane stride 20 B -> fully-consumed cache lines across the wave.
        const float e0 = erow[0];
        const float e1 = erow[1];
        const float e2 = erow[2];
        const float e3 = erow[3];
        const float e4 = erow[4];

        float acc = B2;
#pragma unroll
        for (int d = 0; d < NI; ++d) {
            float h = B1[d]
                    + e0 * W1[0][d]
                    + e1 * W1[1][d]
                    + e2 * W1[2][d]
                    + e3 * W1[3][d]
                    + e4 * W1[4][d];
            // sigmoid
            h = 1.0f / (1.0f + __expf(-h));
            acc += h * W2[d];
        }
        *orow = acc;

        erow += (size_t)NB * NE;
        orow += NB;
    }
}

extern "C" void kernel_launch(void* const* d_in, const int* in_sizes, int n_in,
                              void* d_out, int out_size, void* d_ws, size_t ws_size,
                              hipStream_t stream) {
    const float* E   = (const float*)d_in[0];
    const int*   rix = (const int*)  d_in[1];
    const float* w1  = (const float*)d_in[2];
    const float* b1  = (const float*)d_in[3];
    const float* w2  = (const float*)d_in[4];
    const float* b2  = (const float*)d_in[5];
    float*       out = (float*)d_out;

    dim3 grid(NB / 256, NA / ROWS);   // 16 x 128 = 2048 blocks = 32 waves/CU
    dim3 block(256);
    hipLaunchKernelGGL(e2e_kernel, grid, block, 0, stream, E, rix, w1, b1, w2, b2, out);
}

// Round 2
// 476.077 us; speedup vs baseline: 1.0055x; 1.0055x over previous
//
#include <hip/hip_runtime.h>
#include <hip/hip_bf16.h>

// EmbeddingToExpression: out[a,b] = sigmoid(E[a,b,:] @ W1[rix[b]] + b1[rix[b]]) @ W2[rix[b]] + b2[rix[b]]
// A = 4096 cells, B = 4096 regions_b, NE = 5, NI = 5.
// Memory-bound: 335 MB E read + 67 MB out write => ~64 us floor at 6.3 TB/s.
//
// R1 lesson: direct per-thread E reads have 20-B lane stride (5 dword loads,
// each spanning 20 cache lines per wave) -> 0.84 TB/s. Fix: stage E through
// LDS with perfectly coalesced float4 loads (16 B/lane), then read at stride
// 5 from LDS (gcd(5,32)=1 -> 2 lanes/bank = conflict-free).

#define NA 4096
#define NB 4096
#define NE 5
#define NI 5
#define ROWS 32        // rows of 'a' per block
#define SROWS 4        // rows staged per chunk (one wave per row)
#define ROW_FLOATS (256 * NE)   // 1280 floats per (row, 256-col) slice

__global__ __launch_bounds__(256) void e2e_kernel(
    const float* __restrict__ E,     // [NA, NB, NE]
    const int*   __restrict__ rix,   // [NB]
    const float* __restrict__ w1,    // [R, NE, NI]
    const float* __restrict__ b1,    // [R, NI]
    const float* __restrict__ w2,    // [R, NI, 1]
    const float* __restrict__ b2,    // [R, 1]
    float*       __restrict__ out)   // [NA, NB]
{
    __shared__ float lds[SROWS * ROW_FLOATS];   // 20 KB

    const int tid  = threadIdx.x;
    const int b0   = blockIdx.x * 256;
    const int b    = b0 + tid;                  // this thread's column
    const int a0   = blockIdx.y * ROWS;
    const int srow = tid >> 6;                  // 0..3: which staged row this wave loads
    const int lane = tid & 63;

    const int r = rix[b];

    // Per-region params -> registers (36 floats), amortized over ROWS rows.
    float W1[NE][NI];
    const float* w1p = w1 + (size_t)r * (NE * NI);
#pragma unroll
    for (int c = 0; c < NE; ++c)
#pragma unroll
        for (int d = 0; d < NI; ++d)
            W1[c][d] = w1p[c * NI + d];

    float B1[NI], W2[NI];
    const float* b1p = b1 + (size_t)r * NI;
    const float* w2p = w2 + (size_t)r * NI;
#pragma unroll
    for (int d = 0; d < NI; ++d) {
        B1[d] = b1p[d];
        W2[d] = w2p[d];
    }
    const float B2 = b2[r];

#pragma unroll 1
    for (int chunk = 0; chunk < ROWS / SROWS; ++chunk) {
        // ---- stage SROWS rows, one wave per row, float4 fully coalesced ----
        const int a_ld = a0 + chunk * SROWS + srow;
        const float4* src = (const float4*)(E + ((size_t)a_ld * NB + b0) * NE);
        float4* dst = (float4*)(lds + srow * ROW_FLOATS);
#pragma unroll
        for (int j = 0; j < ROW_FLOATS / 4 / 64; ++j)   // 5 float4 per lane
            dst[lane + j * 64] = src[lane + j * 64];

        __syncthreads();

        // ---- compute SROWS outputs for this thread's column ----
#pragma unroll
        for (int s = 0; s < SROWS; ++s) {
            const float* e = lds + s * ROW_FLOATS + tid * NE;
            const float e0 = e[0], e1 = e[1], e2 = e[2], e3 = e[3], e4 = e[4];

            float acc = B2;
#pragma unroll
            for (int d = 0; d < NI; ++d) {
                float h = B1[d]
                        + e0 * W1[0][d]
                        + e1 * W1[1][d]
                        + e2 * W1[2][d]
                        + e3 * W1[3][d]
                        + e4 * W1[4][d];
                h = 1.0f / (1.0f + __expf(-h));
                acc += h * W2[d];
            }
            out[(size_t)(a0 + chunk * SROWS + s) * NB + b] = acc;
        }

        __syncthreads();   // protect LDS before next chunk overwrites
    }
}

extern "C" void kernel_launch(void* const* d_in, const int* in_sizes, int n_in,
                              void* d_out, int out_size, void* d_ws, size_t ws_size,
                              hipStream_t stream) {
    const float* E   = (const float*)d_in[0];
    const int*   rix = (const int*)  d_in[1];
    const float* w1  = (const float*)d_in[2];
    const float* b1  = (const float*)d_in[3];
    const float* w2  = (const float*)d_in[4];
    const float* b2  = (const float*)d_in[5];
    float*       out = (float*)d_out;

    dim3 grid(NB / 256, NA / ROWS);   // 16 x 128 = 2048 blocks
    dim3 block(256);
    hipLaunchKernelGGL(e2e_kernel, grid, block, 0, stream, E, rix, w1, b1, w2, b2, out);
}